// Round 20
// baseline (37.690 us; speedup 1.0000x reference)
//
#include <hip/hip_runtime.h>
#include <hip/hip_fp16.h>
#include <float.h>

constexpr int KMAX  = 11;    // KS_MAX
constexpr int SEQ   = 512;   // SEQ_LEN
constexpr int NB    = 64;    // BATCH
constexpr int NBB   = 8;     // batches per block (8 groups)
constexpr int NGRP  = NB / NBB;
constexpr int KPB   = 4;     // kernels per block = 1 per wave
constexpr int SBASE = 512;   // fixed window: slot = s + 512
constexpr int WSLOT = 1600;  // s in [-512, 1088). Bound proof: pad>0 => c<=2 and
                             // lout<=1022 => s_max = lout+62+2 = 1086; pad=0 =>
                             // lout+c_max = 512 => s_max = 574. s_min = -2*pad >= -510.

__device__ __forceinline__ unsigned h2b(__half2 h) { unsigned u; __builtin_memcpy(&u, &h, 4); return u; }
__device__ __forceinline__ __half2  b2h(unsigned u) { __half2 h; __builtin_memcpy(&h, &u, 4); return h; }

// ROCm 7.2 has no __hmax2/__hmin2 — use VOP3P directly.
__device__ __forceinline__ unsigned pkmax(unsigned a, unsigned b) {
    unsigned d; asm("v_pk_max_f16 %0, %1, %2" : "=v"(d) : "v"(a), "v"(b)); return d;
}
__device__ __forceinline__ unsigned pkadd(unsigned a, unsigned b) { return h2b(__hadd2(b2h(a), b2h(b))); }
__device__ __forceinline__ __half2 h2max(__half2 a, __half2 b) { return b2h(pkmax(h2b(a), h2b(b))); }
// fused (a*b+c) clamped to [0,1] — the whole count update in one VOP3P
__device__ __forceinline__ unsigned pkfma_clamp(unsigned a, unsigned b, unsigned c) {
    unsigned d; asm("v_pk_fma_f16 %0, %1, %2, %3 clamp" : "=v"(d) : "v"(a), "v"(b), "v"(c)); return d;
}

template<int CTRL>
__device__ __forceinline__ unsigned dppmov(unsigned old, unsigned v) {
    return (unsigned)__builtin_amdgcn_update_dpp((int)old, (int)v, CTRL, 0xF, 0xF, false);
}
constexpr unsigned NEGINF2 = 0xFC00FC00u;   // -inf | -inf (f16 pair)

__device__ __forceinline__ unsigned dpp_redmax(unsigned x) {
    x = pkmax(x, dppmov<0xB1 >(NEGINF2, x));  // quad_perm xor1
    x = pkmax(x, dppmov<0x4E >(NEGINF2, x));  // quad_perm xor2
    x = pkmax(x, dppmov<0x141>(NEGINF2, x));  // row_half_mirror
    x = pkmax(x, dppmov<0x140>(NEGINF2, x));  // row_mirror
    x = pkmax(x, dppmov<0x142>(NEGINF2, x));  // row_bcast15
    x = pkmax(x, dppmov<0x143>(NEGINF2, x));  // row_bcast31
    return x;                                  // lane 63 valid
}
__device__ __forceinline__ unsigned dpp_redadd(unsigned x) {
    x = pkadd(x, dppmov<0xB1 >(0u, x));
    x = pkadd(x, dppmov<0x4E >(0u, x));
    x = pkadd(x, dppmov<0x141>(0u, x));
    x = pkadd(x, dppmov<0x140>(0u, x));
    x = pkadd(x, dppmov<0x142>(0u, x));
    x = pkadd(x, dppmov<0x143>(0u, x));
    return x;                                  // lane 63 valid
}

// ======================= conv body (byte-identical to R19) =======================
template<int NJ>
__device__ __forceinline__ void conv_wave(
    const char* __restrict__ xsc, int mrow, int lout, int lane, unsigned ctermb,
    unsigned (&um)[4], unsigned (&uc)[4])
{
    const __half2 zero2 = __float2half2_rn(0.f);
    const __half2 nbig2 = __float2half2_rn(-65504.f);
    const unsigned C4b  = 0x74007400u;   // f16 pair {2^14, 2^14}

    int addr[NJ]; __half2 wr[NJ];
#pragma unroll
    for (int j = 0; j < NJ; ++j) {
        const int c = __builtin_amdgcn_readlane(mrow, 1 + j);
        wr[j]   = b2h((unsigned)__builtin_amdgcn_readlane(mrow, 12 + j));
        addr[j] = (lane + c + SBASE) * 16;
    }
    __half2 mx2[4], ct2[4];
#pragma unroll
    for (int m = 0; m < 4; ++m) { mx2[m] = nbig2; ct2[m] = zero2; }

    const int nfull = lout >> 6;
    const int ng4   = nfull >> 2;

    for (int g = 0; g < ng4; ++g) {       // groups of 4 full chunks, immediate offsets
#pragma unroll
        for (int u = 0; u < 4; ++u) {
            uint4 d[NJ];
#pragma unroll
            for (int j = 0; j < NJ; ++j)
                d[j] = *reinterpret_cast<const uint4*>(xsc + addr[j] + u * 1024);
            __half2 a[4] = {zero2, zero2, zero2, zero2};
#pragma unroll
            for (int j = 0; j < NJ; ++j) {
                a[0] = __hfma2(wr[j], b2h(d[j].x), a[0]);
                a[1] = __hfma2(wr[j], b2h(d[j].y), a[1]);
                a[2] = __hfma2(wr[j], b2h(d[j].z), a[2]);
                a[3] = __hfma2(wr[j], b2h(d[j].w), a[3]);
            }
#pragma unroll
            for (int m = 0; m < 4; ++m) {
                mx2[m] = h2max(mx2[m], a[m]);
                ct2[m] = b2h(pkadd(h2b(ct2[m]), pkfma_clamp(h2b(a[m]), C4b, ctermb)));
            }
        }
#pragma unroll
        for (int j = 0; j < NJ; ++j) addr[j] += 4096;
    }
    for (int u = 0; u < (nfull & 3); ++u) {   // leftover full chunks
        uint4 d[NJ];
#pragma unroll
        for (int j = 0; j < NJ; ++j)
            d[j] = *reinterpret_cast<const uint4*>(xsc + addr[j]);
        __half2 a[4] = {zero2, zero2, zero2, zero2};
#pragma unroll
        for (int j = 0; j < NJ; ++j) {
            a[0] = __hfma2(wr[j], b2h(d[j].x), a[0]);
            a[1] = __hfma2(wr[j], b2h(d[j].y), a[1]);
            a[2] = __hfma2(wr[j], b2h(d[j].z), a[2]);
            a[3] = __hfma2(wr[j], b2h(d[j].w), a[3]);
        }
#pragma unroll
        for (int m = 0; m < 4; ++m) {
            mx2[m] = h2max(mx2[m], a[m]);
            ct2[m] = b2h(pkadd(h2b(ct2[m]), pkfma_clamp(h2b(a[m]), C4b, ctermb)));
        }
#pragma unroll
        for (int j = 0; j < NJ; ++j) addr[j] += 1024;
    }
    const int rem = lout & 63;
    if (rem) {                                 // straddle chunk, lane-masked
        uint4 d[NJ];
#pragma unroll
        for (int j = 0; j < NJ; ++j)
            d[j] = *reinterpret_cast<const uint4*>(xsc + addr[j]);
        __half2 a[4] = {zero2, zero2, zero2, zero2};
#pragma unroll
        for (int j = 0; j < NJ; ++j) {
            a[0] = __hfma2(wr[j], b2h(d[j].x), a[0]);
            a[1] = __hfma2(wr[j], b2h(d[j].y), a[1]);
            a[2] = __hfma2(wr[j], b2h(d[j].z), a[2]);
            a[3] = __hfma2(wr[j], b2h(d[j].w), a[3]);
        }
        const bool tm = lane < rem;
#pragma unroll
        for (int m = 0; m < 4; ++m) {
            a[m] = tm ? a[m] : nbig2;          // -65504*2^14 -> -inf -> clamp -> 0
            mx2[m] = h2max(mx2[m], a[m]);
            ct2[m] = b2h(pkadd(h2b(ct2[m]), pkfma_clamp(h2b(a[m]), C4b, ctermb)));
        }
    }

#pragma unroll
    for (int m = 0; m < 4; ++m) {
        um[m] = dpp_redmax(h2b(mx2[m]));
        uc[m] = dpp_redadd(h2b(ct2[m]));
    }
}

// ======================= fused kernel =======================
// grid (K/4, 8): block = (4 kernels, 8-batch group). 256 threads = 4 waves.
// Prologue replaces the former prep kernel: (1) speculative idx-scan loads
// (rounds 0-3, coalesced) issued first; (2) staging straight from f32 x with
// in-register f16 convert (no xt workspace); (3) barrier; (4) scan ballots
// resolve (data arrived under staging), weight compaction via ballot+shfl into
// the same lane-resident mrow layout. Conv/reduce/epilogue unchanged from R19.
__global__ __launch_bounds__(256, 4)
void rocket_fused(const float* __restrict__ x, const float* __restrict__ w,
                  const int* __restrict__ idx, const float* __restrict__ bias,
                  const int* __restrict__ l_out, float* __restrict__ out,
                  int K, int maxL)
{
    __shared__ __align__(16) unsigned xs_u[WSLOT * 4];   // 25600 B fixed window

    const int kbase = (int)blockIdx.x * KPB;
    const int grp   = blockIdx.y;
    const int tid   = threadIdx.x;
    const int wave  = tid >> 6, lane = tid & 63;

    const int k  = kbase + wave;
    const int kc = min(k, K - 1);                        // safe addr for k >= K

    // ---- (1) speculative tap-scan loads: rounds 0..3, all 11 taps, in flight ----
    int tr[4];
#pragma unroll
    for (int r = 0; r < 4; ++r) tr[r] = min(r * 64 + lane, maxL - 1);
    const int* idk = idx + (size_t)kc * KMAX * (size_t)maxL;
    int vv[KMAX][4];
#pragma unroll
    for (int j = 0; j < KMAX; ++j)
#pragma unroll
        for (int r = 0; r < 4; ++r)
            vv[j][r] = idk[(size_t)j * maxL + tr[r]];

    // ---- (2) hoisted per-wave loads ----
    const int   lout_v = l_out[kc];
    const float bias_v = bias[kc];
    const float wj_v   = (lane < KMAX) ? w[(size_t)kc * KMAX + lane] : 0.f;

    // ---- (3) stage window from f32 x: zeros in fringes, f16-packed data ----
    uint4* xs4 = reinterpret_cast<uint4*>(xs_u);
    const float* xg = x + (size_t)(grp * NBB) * SEQ;
    for (int i = tid; i < WSLOT; i += 256) {
        const int s = i - SBASE;
        if ((unsigned)s >= (unsigned)SEQ) xs4[i] = make_uint4(0u, 0u, 0u, 0u);
    }
#pragma unroll
    for (int h = 0; h < 2; ++h) {
        const int s = tid + h * 256;
        float f[8];
#pragma unroll
        for (int bl = 0; bl < 8; ++bl) f[bl] = xg[bl * SEQ + s];   // coalesced per bl
        unsigned p[4];
#pragma unroll
        for (int q = 0; q < 4; ++q)
            p[q] = h2b(__halves2half2(__float2half_rn(f[2 * q]), __float2half_rn(f[2 * q + 1])));
        xs4[SBASE + s] = make_uint4(p[0], p[1], p[2], p[3]);
    }
    __syncthreads();

    if (k >= K) return;

    // ---- (4) resolve tap offsets (wave-uniform control; data long arrived) ----
    // idx[k,j,t] = clip(t+c, 0, 511); interior value (0 < v < 511) gives c = v - t.
    int cj_lane = 0;                      // lane j will hold c_j
#pragma unroll
    for (int j = 0; j < KMAX; ++j) {
        bool found = false; int cjv = 0;
#pragma unroll
        for (int r = 0; r < 4; ++r) {
            const bool in = (vv[j][r] > 0) && (vv[j][r] < SEQ - 1);
            const unsigned long long mb = __ballot(in);
            if (!found && mb != 0ull) {
                const int fl = __builtin_ctzll(mb);
                const int tf = min(r * 64 + fl, maxL - 1);
                cjv = __shfl(vv[j][r], fl) - tf;
                found = true;
            }
        }
        if (!found) {                     // dense serial fallback from t = 256
            for (int base = 256; base < maxL; base += 64) {
                const int t = base + lane;
                const int v = (t < maxL) ? idk[(size_t)j * maxL + t] : 0;
                const bool in = (v > 0) && (v < SEQ - 1);
                const unsigned long long mb = __ballot(in);
                if (mb != 0ull) {
                    const int fl = __builtin_ctzll(mb);
                    cjv = __shfl(v, fl) - (base + fl);
                    break;
                }
            }
        }
        cj_lane = (lane == j) ? cjv : cj_lane;
    }

    // ---- weight compaction -> lane-resident mrow (same layout as old meta) ----
    unsigned wlb;
    { __half hw = __float2half_rn(wj_v); unsigned short ub;
      __builtin_memcpy(&ub, &hw, 2); wlb = (unsigned)ub | ((unsigned)ub << 16); }
    const unsigned long long nz = __ballot((lane < KMAX) && (wj_v != 0.f));
    const int nj = (int)__popcll(nz);

    int sel = 0;
    if (lane >= 1 && lane <= KMAX) sel = lane - 1;
    else if (lane >= 12 && lane <= 11 + KMAX) sel = lane - 12;
    unsigned long long m = nz;
#pragma unroll
    for (int it = 0; it < KMAX; ++it) m = (it < sel) ? (m & (m - 1)) : m;
    const bool vali = (m != 0ull);
    const int ji = vali ? (int)__builtin_ctzll(m) : 0;
    const int cv = __shfl(cj_lane, ji);
    const int wv = __shfl((int)wlb, ji);
    int mrow = 0;
    if (lane == 0)               mrow = nj;
    else if (lane <= KMAX)       mrow = vali ? cv : 0;   // pads: c=0 (in-window), w=0
    else if (lane <= 11 + KMAX)  mrow = vali ? (int)wv : 0;

    // ---- conv + reduce + epilogue (unchanged) ----
    const int lout  = __builtin_amdgcn_readfirstlane(lout_v);
    const float biasf = __int_as_float(__builtin_amdgcn_readfirstlane(__float_as_int(bias_v)));
    const unsigned ctermb = h2b(__float2half2_rn(biasf * 16384.f));

    unsigned um[4], uc[4];
    const char* xsc = reinterpret_cast<const char*>(xs_u);
    if (nj <= 7)      conv_wave<7 >(xsc, mrow, lout, lane, ctermb, um, uc);
    else if (nj <= 9) conv_wave<9 >(xsc, mrow, lout, lane, ctermb, um, uc);
    else              conv_wave<11>(xsc, mrow, lout, lane, ctermb, um, uc);

    if (lane == 63) {
        const float loutf = (float)lout;
#pragma unroll
        for (int m2 = 0; m2 < 4; ++m2) {
            const __half2 hm = b2h(um[m2]);
            const __half2 hc = b2h(uc[m2]);
            float* o0 = out + (size_t)(grp * NBB + 2 * m2) * (2 * K) + 2 * k;
            o0[0] = __low2float(hm) + biasf;           // deferred bias
            o0[1] = __low2float(hc) / loutf;
            float* o1 = o0 + 2 * K;
            o1[0] = __high2float(hm) + biasf;
            o1[1] = __high2float(hc) / loutf;
        }
    }
}

// ======================= launch =======================
extern "C" void kernel_launch(void* const* d_in, const int* in_sizes, int n_in,
                              void* d_out, int out_size, void* d_ws, size_t ws_size,
                              hipStream_t stream)
{
    const float* x    = (const float*)d_in[0];
    const float* w    = (const float*)d_in[1];
    const float* bias = (const float*)d_in[2];
    const int*   idx  = (const int*)d_in[3];
    // d_in[4] = valid (unused: validity derived exactly from the idx ramp)
    const int*   lout = (const int*)d_in[5];
    float* out = (float*)d_out;

    const int K    = in_sizes[2];               // N_KERNELS
    const int maxL = in_sizes[3] / (K * KMAX);  // idx = [K][KMAX][maxL]

    rocket_fused<<<dim3((K + KPB - 1) / KPB, NGRP), 256, 0, stream>>>(
        x, w, idx, bias, lout, out, K, maxL);
}

// Round 21
// 29.976 us; speedup vs baseline: 1.2574x; 1.2574x over previous
//
#include <hip/hip_runtime.h>
#include <hip/hip_fp16.h>
#include <float.h>

constexpr int KMAX  = 11;    // KS_MAX
constexpr int SEQ   = 512;   // SEQ_LEN
constexpr int NB    = 64;    // BATCH
constexpr int NBB   = 8;     // batches per main block (8 groups)
constexpr int NGRP  = NB / NBB;
constexpr int KPB   = 4;     // kernels per block = 1 per wave
constexpr int MSTR  = 32;    // meta ints per k: [0]=nj [1..11]=c [12..22]=w2bits
constexpr int SBASE = 512;   // fixed window: slot = s + 512
constexpr int WSLOT = 1600;  // s in [-512, 1088)

__device__ __forceinline__ unsigned h2b(__half2 h) { unsigned u; __builtin_memcpy(&u, &h, 4); return u; }
__device__ __forceinline__ __half2  b2h(unsigned u) { __half2 h; __builtin_memcpy(&h, &u, 4); return h; }

// ROCm 7.2 has no __hmax2/__hmin2 — use VOP3P directly.
__device__ __forceinline__ unsigned pkmax(unsigned a, unsigned b) {
    unsigned d; asm("v_pk_max_f16 %0, %1, %2" : "=v"(d) : "v"(a), "v"(b)); return d;
}
__device__ __forceinline__ unsigned pkadd(unsigned a, unsigned b) { return h2b(__hadd2(b2h(a), b2h(b))); }
__device__ __forceinline__ __half2 h2max(__half2 a, __half2 b) { return b2h(pkmax(h2b(a), h2b(b))); }
// fused (a*b+c) clamped to [0,1] — the whole count update in one VOP3P
__device__ __forceinline__ unsigned pkfma_clamp(unsigned a, unsigned b, unsigned c) {
    unsigned d; asm("v_pk_fma_f16 %0, %1, %2, %3 clamp" : "=v"(d) : "v"(a), "v"(b), "v"(c)); return d;
}

template<int CTRL>
__device__ __forceinline__ unsigned dppmov(unsigned old, unsigned v) {
    return (unsigned)__builtin_amdgcn_update_dpp((int)old, (int)v, CTRL, 0xF, 0xF, false);
}
constexpr unsigned NEGINF2 = 0xFC00FC00u;   // -inf | -inf (f16 pair)

__device__ __forceinline__ unsigned dpp_redmax(unsigned x) {
    x = pkmax(x, dppmov<0xB1 >(NEGINF2, x));  // quad_perm xor1
    x = pkmax(x, dppmov<0x4E >(NEGINF2, x));  // quad_perm xor2
    x = pkmax(x, dppmov<0x141>(NEGINF2, x));  // row_half_mirror
    x = pkmax(x, dppmov<0x140>(NEGINF2, x));  // row_mirror
    x = pkmax(x, dppmov<0x142>(NEGINF2, x));  // row_bcast15
    x = pkmax(x, dppmov<0x143>(NEGINF2, x));  // row_bcast31
    return x;                                  // lane 63 valid
}
__device__ __forceinline__ unsigned dpp_redadd(unsigned x) {
    x = pkadd(x, dppmov<0xB1 >(0u, x));
    x = pkadd(x, dppmov<0x4E >(0u, x));
    x = pkadd(x, dppmov<0x141>(0u, x));
    x = pkadd(x, dppmov<0x140>(0u, x));
    x = pkadd(x, dppmov<0x142>(0u, x));
    x = pkadd(x, dppmov<0x143>(0u, x));
    return x;                                  // lane 63 valid
}

// ======================= prep kernel =======================
// blocks [0, K):    meta via AFFINE derivation: idx rows are affine in j
//                   (c_j = c_0 + j*d), so only rows 0 and 1 are probed, each at
//                   two fixed coalesced rounds t in [0,64) and [448,512) which
//                   provably intersect every possible interior run. 4 loads,
//                   zero serial scanning. Dense fallback kept for safety.
// blocks [K, K+32): transpose+convert x (NB x SEQ f32) -> xt16[g][s][8] f16
__global__ __launch_bounds__(256)
void prep_kernel(const float* __restrict__ x, const float* __restrict__ w,
                 const int* __restrict__ idx, int* __restrict__ meta,
                 unsigned short* __restrict__ xt, int K, int maxL)
{
    const int tid = threadIdx.x;
    if ((int)blockIdx.x >= K) {
        const int j  = ((int)blockIdx.x - K) * 256 + tid;   // 0..8191
        const int b  = j >> 7, s4 = j & 127;
        const float4 v = reinterpret_cast<const float4*>(x)[b * (SEQ / 4) + s4];
        const int g = b >> 3, bl = b & 7;
        unsigned short* dst = xt + ((size_t)g * SEQ + s4 * 4) * NBB + bl;
        __half h;
        h = __float2half_rn(v.x); __builtin_memcpy(&dst[0 * NBB], &h, 2);
        h = __float2half_rn(v.y); __builtin_memcpy(&dst[1 * NBB], &h, 2);
        h = __float2half_rn(v.z); __builtin_memcpy(&dst[2 * NBB], &h, 2);
        h = __float2half_rn(v.w); __builtin_memcpy(&dst[3 * NBB], &h, 2);
        return;
    }

    if (tid >= 64) return;               // wave 0 only; no barriers below
    const int k = blockIdx.x, lane = tid;
    const int* idk = idx + (size_t)k * KMAX * (size_t)maxL;

    // ---- 4 coalesced probe loads, all in flight together ----
    const int t0 = min(lane, maxL - 1);
    const int t7 = min(448 + lane, maxL - 1);
    const int v00 = idk[t0];
    const int v07 = idk[t7];
    const int v10 = idk[maxL + t0];
    const int v17 = idk[maxL + t7];
    const float w_l = (lane < KMAX) ? w[(size_t)k * KMAX + lane] : 0.f;

    // interior value (0 < v < 511) is unclipped: c = v - t
    int c0 = 0, c1 = 0;
    bool ok0 = false, ok1 = false;
    {
        unsigned long long m = __ballot((v00 > 0) && (v00 < SEQ - 1));
        if (m) { const int fl = __builtin_ctzll(m); c0 = __shfl(v00, fl) - min(fl, maxL - 1); ok0 = true; }
        else {
            m = __ballot((v07 > 0) && (v07 < SEQ - 1));
            if (m) { const int fl = __builtin_ctzll(m); c0 = __shfl(v07, fl) - min(448 + fl, maxL - 1); ok0 = true; }
        }
    }
    {
        unsigned long long m = __ballot((v10 > 0) && (v10 < SEQ - 1));
        if (m) { const int fl = __builtin_ctzll(m); c1 = __shfl(v10, fl) - min(fl, maxL - 1); ok1 = true; }
        else {
            m = __ballot((v17 > 0) && (v17 < SEQ - 1));
            if (m) { const int fl = __builtin_ctzll(m); c1 = __shfl(v17, fl) - min(448 + fl, maxL - 1); ok1 = true; }
        }
    }
    // dense fallback (wave-uniform; should never trigger per the coverage proof)
    if (!ok0) {
        for (int base = 0; base < maxL; base += 64) {
            const int t = base + lane;
            const int v = (t < maxL) ? idk[t] : 0;
            const unsigned long long m = __ballot((v > 0) && (v < SEQ - 1));
            if (m) { const int fl = __builtin_ctzll(m); c0 = __shfl(v, fl) - (base + fl); break; }
        }
    }
    if (!ok1) {
        for (int base = 0; base < maxL; base += 64) {
            const int t = base + lane;
            const int v = (t < maxL) ? idk[maxL + t] : 0;
            const unsigned long long m = __ballot((v > 0) && (v < SEQ - 1));
            if (m) { const int fl = __builtin_ctzll(m); c1 = __shfl(v, fl) - (base + fl); break; }
        }
    }
    const int d = c1 - c0;               // c_j = c0 + j*d (affine in j)

    if (lane == 0) {
        int* mk = meta + (size_t)k * MSTR;
        int n = 0;
        for (int j = 0; j < KMAX; ++j) {
            const float wj = __int_as_float(__builtin_amdgcn_readlane(__float_as_int(w_l), j));
            if (wj != 0.0f) {
                mk[1 + n] = c0 + j * d;  // exact c_j, in [-510, 510] for real taps
                __half hw = __float2half_rn(wj);
                unsigned short ub; __builtin_memcpy(&ub, &hw, 2);
                mk[12 + n] = (unsigned)ub | ((unsigned)ub << 16);
                ++n;
            }
        }
        for (int jj = n; jj < KMAX; ++jj) { mk[1 + jj] = 0; mk[12 + jj] = 0; }  // in-window, w=0
        mk[0] = n;
    }
}

// ======================= main kernel (byte-identical to R19) =======================
template<int NJ>
__device__ __forceinline__ void conv_wave(
    const char* __restrict__ xsc, int mrow, int lout, int lane, unsigned ctermb,
    unsigned (&um)[4], unsigned (&uc)[4])
{
    const __half2 zero2 = __float2half2_rn(0.f);
    const __half2 nbig2 = __float2half2_rn(-65504.f);
    const unsigned C4b  = 0x74007400u;   // f16 pair {2^14, 2^14}

    int addr[NJ]; __half2 wr[NJ];
#pragma unroll
    for (int j = 0; j < NJ; ++j) {
        const int c = __builtin_amdgcn_readlane(mrow, 1 + j);
        wr[j]   = b2h((unsigned)__builtin_amdgcn_readlane(mrow, 12 + j));
        addr[j] = (lane + c + SBASE) * 16;
    }
    __half2 mx2[4], ct2[4];
#pragma unroll
    for (int m = 0; m < 4; ++m) { mx2[m] = nbig2; ct2[m] = zero2; }

    const int nfull = lout >> 6;
    const int ng4   = nfull >> 2;

    for (int g = 0; g < ng4; ++g) {       // groups of 4 full chunks, immediate offsets
#pragma unroll
        for (int u = 0; u < 4; ++u) {
            uint4 d[NJ];
#pragma unroll
            for (int j = 0; j < NJ; ++j)
                d[j] = *reinterpret_cast<const uint4*>(xsc + addr[j] + u * 1024);
            __half2 a[4] = {zero2, zero2, zero2, zero2};
#pragma unroll
            for (int j = 0; j < NJ; ++j) {
                a[0] = __hfma2(wr[j], b2h(d[j].x), a[0]);
                a[1] = __hfma2(wr[j], b2h(d[j].y), a[1]);
                a[2] = __hfma2(wr[j], b2h(d[j].z), a[2]);
                a[3] = __hfma2(wr[j], b2h(d[j].w), a[3]);
            }
#pragma unroll
            for (int m = 0; m < 4; ++m) {
                mx2[m] = h2max(mx2[m], a[m]);
                ct2[m] = b2h(pkadd(h2b(ct2[m]), pkfma_clamp(h2b(a[m]), C4b, ctermb)));
            }
        }
#pragma unroll
        for (int j = 0; j < NJ; ++j) addr[j] += 4096;
    }
    for (int u = 0; u < (nfull & 3); ++u) {   // leftover full chunks
        uint4 d[NJ];
#pragma unroll
        for (int j = 0; j < NJ; ++j)
            d[j] = *reinterpret_cast<const uint4*>(xsc + addr[j]);
        __half2 a[4] = {zero2, zero2, zero2, zero2};
#pragma unroll
        for (int j = 0; j < NJ; ++j) {
            a[0] = __hfma2(wr[j], b2h(d[j].x), a[0]);
            a[1] = __hfma2(wr[j], b2h(d[j].y), a[1]);
            a[2] = __hfma2(wr[j], b2h(d[j].z), a[2]);
            a[3] = __hfma2(wr[j], b2h(d[j].w), a[3]);
        }
#pragma unroll
        for (int m = 0; m < 4; ++m) {
            mx2[m] = h2max(mx2[m], a[m]);
            ct2[m] = b2h(pkadd(h2b(ct2[m]), pkfma_clamp(h2b(a[m]), C4b, ctermb)));
        }
#pragma unroll
        for (int j = 0; j < NJ; ++j) addr[j] += 1024;
    }
    const int rem = lout & 63;
    if (rem) {                                 // straddle chunk, lane-masked
        uint4 d[NJ];
#pragma unroll
        for (int j = 0; j < NJ; ++j)
            d[j] = *reinterpret_cast<const uint4*>(xsc + addr[j]);
        __half2 a[4] = {zero2, zero2, zero2, zero2};
#pragma unroll
        for (int j = 0; j < NJ; ++j) {
            a[0] = __hfma2(wr[j], b2h(d[j].x), a[0]);
            a[1] = __hfma2(wr[j], b2h(d[j].y), a[1]);
            a[2] = __hfma2(wr[j], b2h(d[j].z), a[2]);
            a[3] = __hfma2(wr[j], b2h(d[j].w), a[3]);
        }
        const bool tm = lane < rem;
#pragma unroll
        for (int m = 0; m < 4; ++m) {
            a[m] = tm ? a[m] : nbig2;          // -65504*2^14 -> -inf -> clamp -> 0
            mx2[m] = h2max(mx2[m], a[m]);
            ct2[m] = b2h(pkadd(h2b(ct2[m]), pkfma_clamp(h2b(a[m]), C4b, ctermb)));
        }
    }

#pragma unroll
    for (int m = 0; m < 4; ++m) {
        um[m] = dpp_redmax(h2b(mx2[m]));
        uc[m] = dpp_redadd(h2b(ct2[m]));
    }
}

__global__ __launch_bounds__(256, 4)
void rocket_main(const unsigned short* __restrict__ xt, const int* __restrict__ meta,
                 const float* __restrict__ bias, const int* __restrict__ l_out,
                 float* __restrict__ out, int K)
{
    __shared__ __align__(16) unsigned xs_u[WSLOT * 4];   // 25600 B fixed window

    const int kbase = (int)blockIdx.x * KPB;
    const int grp   = blockIdx.y;
    const int tid   = threadIdx.x;
    const int wave  = tid >> 6, lane = tid & 63;

    // ---- hoisted per-wave loads: issued BEFORE staging, consumed after barrier ----
    const int k  = kbase + wave;
    const int kc = min(k, K - 1);                        // safe addr for k >= K
    const int   mrow_v = meta[(size_t)kc * MSTR + (lane & 31)];
    const int   lout_v = l_out[kc];
    const float bias_v = bias[kc];

    // ---- stage fixed window (zeros outside s in [0,512)); conflict-free b128 ----
    float4* xs4 = reinterpret_cast<float4*>(xs_u);
    const float4* src = reinterpret_cast<const float4*>(xt + (size_t)grp * SEQ * NBB);
    const float4 z4 = make_float4(0.f, 0.f, 0.f, 0.f);
    for (int i = tid; i < WSLOT; i += 256) {
        const int s = i - SBASE;
        xs4[i] = ((unsigned)s < (unsigned)SEQ) ? src[s] : z4;
    }
    __syncthreads();

    if (k >= K) return;

    const int nj    = __builtin_amdgcn_readlane(mrow_v, 0);
    const int lout  = __builtin_amdgcn_readfirstlane(lout_v);
    const float biasf = __int_as_float(__builtin_amdgcn_readfirstlane(__float_as_int(bias_v)));
    const unsigned ctermb = h2b(__float2half2_rn(biasf * 16384.f));

    unsigned um[4], uc[4];
    const char* xsc = reinterpret_cast<const char*>(xs_u);
    if (nj <= 7)      conv_wave<7 >(xsc, mrow_v, lout, lane, ctermb, um, uc);
    else if (nj <= 9) conv_wave<9 >(xsc, mrow_v, lout, lane, ctermb, um, uc);
    else              conv_wave<11>(xsc, mrow_v, lout, lane, ctermb, um, uc);

    // ---- lane 63 finalizes: 8 batches x {max, ppv} ----
    if (lane == 63) {
        const float loutf = (float)lout;
#pragma unroll
        for (int m = 0; m < 4; ++m) {
            const __half2 hm = b2h(um[m]);
            const __half2 hc = b2h(uc[m]);
            float* o0 = out + (size_t)(grp * NBB + 2 * m) * (2 * K) + 2 * k;
            o0[0] = __low2float(hm) + biasf;           // deferred bias
            o0[1] = __low2float(hc) / loutf;
            float* o1 = o0 + 2 * K;
            o1[0] = __high2float(hm) + biasf;
            o1[1] = __high2float(hc) / loutf;
        }
    }
}

// ======================= launch =======================
extern "C" void kernel_launch(void* const* d_in, const int* in_sizes, int n_in,
                              void* d_out, int out_size, void* d_ws, size_t ws_size,
                              hipStream_t stream)
{
    const float* x    = (const float*)d_in[0];
    const float* w    = (const float*)d_in[1];
    const float* bias = (const float*)d_in[2];
    const int*   idx  = (const int*)d_in[3];
    // d_in[4] = valid (unused: validity derived exactly from the idx ramp)
    const int*   lout = (const int*)d_in[5];
    float* out = (float*)d_out;

    const int K    = in_sizes[2];               // N_KERNELS
    const int maxL = in_sizes[3] / (K * KMAX);  // idx = [K][KMAX][maxL]

    // workspace: meta (K*32 ints) | xt16 (NB*SEQ f16), 256B-aligned split
    int* meta = (int*)d_ws;
    size_t meta_bytes = ((size_t)K * MSTR * sizeof(int) + 255) & ~(size_t)255;
    unsigned short* xt = (unsigned short*)((char*)d_ws + meta_bytes);

    prep_kernel<<<K + 32, 256, 0, stream>>>(x, w, idx, meta, xt, K, maxL);
    rocket_main<<<dim3((K + KPB - 1) / KPB, NGRP), 256, 0, stream>>>(xt, meta, bias, lout, out, K);
}